// Round 6
// baseline (52.819 us; speedup 1.0000x reference)
//
#include <hip/hip_runtime.h>

// Problem constants (match reference)
#define BB 64
#define N_WAY 5
#define N_SHOT 5
#define QUERY 15
#define NUM_SLOT 8
#define DD 640
#define IMGS (N_WAY * QUERY)      // 75
#define NS (BB * N_WAY * N_SHOT)  // 1600 support rows
#define NROWS 6400                // total rows
#define ROWSZ (NUM_SLOT * DD)     // 5120 floats per row
#define F4_PER_SLOT 160           // 640/4
#define NELEM (BB * IMGS)         // 4800 loss elements
#define NGROUP (BB * N_WAY)       // 320 support groups

// ---------------- K1: single streaming pass over out_f ----------------
// rowmean[6400][8] (per-row slot means), proto_all[320][8][640] (shot-means,
// all slots), pn2_all[320][8] (||proto||^2, all slots).
__global__ __launch_bounds__(256) void k_pass1(const float* __restrict__ out_f,
                                               float* __restrict__ rowmean,
                                               float* __restrict__ proto_all,
                                               float* __restrict__ pn2_all) {
    int b = blockIdx.x;
    int t = threadIdx.x;
    int slot = t >> 5;            // 0..7
    int l = t & 31;
    if (b < NGROUP) {
        const int g = b;          // support group j*5+c
        float4 acc[5];
        #pragma unroll
        for (int k = 0; k < 5; ++k) acc[k] = make_float4(0.f, 0.f, 0.f, 0.f);
        #pragma unroll
        for (int sh = 0; sh < N_SHOT; ++sh) {
            const float4* p = (const float4*)(out_f +
                ((size_t)((g * N_SHOT + sh) * NUM_SLOT + slot)) * DD);
            float s = 0.f;
            #pragma unroll
            for (int k = 0; k < 5; ++k) {
                float4 v = p[l + k * 32];
                acc[k].x += v.x; acc[k].y += v.y; acc[k].z += v.z; acc[k].w += v.w;
                s += (v.x + v.y) + (v.z + v.w);
            }
            #pragma unroll
            for (int off = 16; off; off >>= 1) s += __shfl_down(s, off, 32);
            if (l == 0) rowmean[(g * N_SHOT + sh) * NUM_SLOT + slot] = s * (1.f / DD);
        }
        float4* pp = (float4*)(proto_all + ((size_t)(g * NUM_SLOT + slot)) * DD);
        float ssq = 0.f;
        #pragma unroll
        for (int k = 0; k < 5; ++k) {
            acc[k].x *= 0.2f; acc[k].y *= 0.2f; acc[k].z *= 0.2f; acc[k].w *= 0.2f;
            pp[l + k * 32] = acc[k];
            ssq += acc[k].x * acc[k].x + acc[k].y * acc[k].y
                 + acc[k].z * acc[k].z + acc[k].w * acc[k].w;
        }
        #pragma unroll
        for (int off = 16; off; off >>= 1) ssq += __shfl_down(ssq, off, 32);
        if (l == 0) pn2_all[g * NUM_SLOT + slot] = ssq;
    } else {
        int r = NS + (b - NGROUP);   // query row
        const float4* p = (const float4*)(out_f + (size_t)r * ROWSZ) + slot * F4_PER_SLOT;
        float s = 0.f;
        #pragma unroll
        for (int k = 0; k < 5; ++k) {
            float4 v = p[l + k * 32];
            s += (v.x + v.y) + (v.z + v.w);
        }
        #pragma unroll
        for (int off = 16; off; off >>= 1) s += __shfl_down(s, off, 32);
        if (l == 0) rowmean[r * NUM_SLOT + slot] = s * (1.f / DD);
    }
}

// ---------------- K2: one block per loss element ----------------
// Each block redundantly computes the (cheap) cover-select and the argmax over
// steps 0..m (== prefix value at m), then one element's two dot-score paths.
// part[bid] = float4(nll1, nll2, acc1, acc2).
__global__ __launch_bounds__(256) void k_elem(const float* __restrict__ out_f,
                                              const float* __restrict__ rowmean,
                                              const float* __restrict__ proto_all,
                                              const float* __restrict__ pn2_all,
                                              const int* __restrict__ labels_query,
                                              float4* __restrict__ part) {
    int bid = blockIdx.x;          // j*75 + m
    int j = bid / IMGS, m = bid - j * IMGS;
    int t = threadIdx.x;           // 256
    int wave = t >> 6, lane = t & 63;

    __shared__ __align__(16) float qb[IMGS * NUM_SLOT];  // 600
    __shared__ float supm[N_WAY * NUM_SLOT];
    __shared__ int   msS[N_WAY];
    __shared__ int   kkS;
    __shared__ float p2S[N_WAY];
    __shared__ float red[4][10];

    // stage query row-means (t<150, float4) and support slot-means (wave 3)
    const float* qbase = rowmean + (size_t)(NS + j * IMGS) * NUM_SLOT;
    if (t < 150) ((float4*)qb)[t] = ((const float4*)qbase)[t];
    if (t >= 192 && t < 192 + N_WAY * NUM_SLOT) {
        int idx = t - 192;
        int c = idx >> 3, s = idx & 7;
        const float* sb = rowmean + (size_t)j * (N_WAY * N_SHOT * NUM_SLOT)
                          + c * (N_SHOT * NUM_SLOT) + s;
        supm[idx] = (sb[0] + sb[8] + sb[16] + sb[24] + sb[32]) * 0.2f;
    }
    __syncthreads();

    // greedy cover select (serial, tiny; first-occurrence among untaken)
    if (t == 0) {
        unsigned taken = 0u;
        #pragma unroll
        for (int c = 0; c < N_WAY; ++c) {
            float best = -3.0e38f; int bi = 0;
            #pragma unroll
            for (int s = 0; s < NUM_SLOT; ++s) {
                float v = supm[c * NUM_SLOT + s];
                if (!((taken >> s) & 1u) && v > best) { best = v; bi = s; }
            }
            taken |= (1u << bi);
            msS[c] = bi;
        }
    }
    __syncthreads();

    if (t < N_WAY) p2S[t] = pn2_all[(j * N_WAY + t) * NUM_SLOT + msS[t]];

    if (wave == 0) {
        // argmax over flat candidates l = s*5+c, s in [0, m]; first occurrence
        // == min flat index among maxima (value-then-index reduce).
        float v = -3.0e38f; int idx = 0x7fffffff;
        #pragma unroll
        for (int rep = 0; rep < 2; ++rep) {
            int s = lane + rep * 64;
            if (s <= m) {
                const float* q = &qb[s * NUM_SLOT];
                #pragma unroll
                for (int c = 0; c < N_WAY; ++c) {
                    float x = q[msS[c]];
                    if (x > v) { v = x; idx = s * N_WAY + c; }  // ascending order + strict >
                }
            }
        }
        #pragma unroll
        for (int off = 32; off; off >>= 1) {
            float ov = __shfl_down(v, off, 64);
            int   oi = __shfl_down(idx, off, 64);
            if (ov > v || (ov == v && oi < idx)) { v = ov; idx = oi; }
        }
        if (lane == 0) kkS = idx;
    }
    __syncthreads();

    int ms1 = msS[m / QUERY];
    int kk = kkS;
    int s2 = kk / N_WAY, c2 = kk - s2 * N_WAY;
    int ms2 = msS[c2];

    float s1[N_WAY] = {0, 0, 0, 0, 0};
    float s2a[N_WAY] = {0, 0, 0, 0, 0};
    if (t < F4_PER_SLOT) {
        const float4* q1 = (const float4*)(out_f + (size_t)(NS + bid) * ROWSZ + ms1 * DD);
        const float4* q2 = (const float4*)(out_f +
            (size_t)(NS + j * IMGS + s2) * ROWSZ + ms2 * DD);
        float4 a = q1[t];
        float4 bq = q2[t];
        #pragma unroll
        for (int n = 0; n < N_WAY; ++n) {
            const float4* pr = (const float4*)(proto_all +
                ((size_t)((j * N_WAY + n) * NUM_SLOT + msS[n])) * DD);
            float4 p = pr[t];
            s1[n]  += a.x * p.x + a.y * p.y + a.z * p.z + a.w * p.w;
            s2a[n] += bq.x * p.x + bq.y * p.y + bq.z * p.z + bq.w * p.w;
        }
    }
    #pragma unroll
    for (int n = 0; n < N_WAY; ++n) {
        #pragma unroll
        for (int off = 32; off; off >>= 1) {
            s1[n]  += __shfl_down(s1[n],  off, 64);
            s2a[n] += __shfl_down(s2a[n], off, 64);
        }
    }
    if (lane == 0) {
        #pragma unroll
        for (int n = 0; n < N_WAY; ++n) { red[wave][n] = s1[n]; red[wave][5 + n] = s2a[n]; }
    }
    __syncthreads();
    if (t == 0) {
        int label = labels_query[bid];
        float nll1, nll2, acc1, acc2;
        // path 1: score_n = 2 q.p_n - ||p_n||^2 (||q||^2 cancels in log_softmax/argmax)
        {
            float li[N_WAY]; float mx = -3.0e38f;
            #pragma unroll
            for (int n = 0; n < N_WAY; ++n) {
                float sc = red[0][n] + red[1][n] + red[2][n] + red[3][n];
                li[n] = 2.f * sc - p2S[n]; mx = fmaxf(mx, li[n]);
            }
            float se = 0.f;
            #pragma unroll
            for (int n = 0; n < N_WAY; ++n) se += expf(li[n] - mx);
            float lse = mx + logf(se);
            int bi = 0; float bvv = li[0];
            #pragma unroll
            for (int n = 1; n < N_WAY; ++n) if (li[n] > bvv) { bvv = li[n]; bi = n; }
            nll1 = -(li[label] - lse);
            acc1 = (bi == label) ? 1.f : 0.f;
        }
        // path 2
        {
            float li[N_WAY]; float mx = -3.0e38f;
            #pragma unroll
            for (int n = 0; n < N_WAY; ++n) {
                float sc = red[0][5 + n] + red[1][5 + n] + red[2][5 + n] + red[3][5 + n];
                li[n] = 2.f * sc - p2S[n]; mx = fmaxf(mx, li[n]);
            }
            float se = 0.f;
            #pragma unroll
            for (int n = 0; n < N_WAY; ++n) se += expf(li[n] - mx);
            float lse = mx + logf(se);
            int bi = 0; float bvv = li[0];
            #pragma unroll
            for (int n = 1; n < N_WAY; ++n) if (li[n] > bvv) { bvv = li[n]; bi = n; }
            nll2 = -(li[label] - lse);
            acc2 = (bi == label) ? 1.f : 0.f;
        }
        part[bid] = make_float4(nll1, nll2, acc1, acc2);
    }
}

// ---------------- K3: final deterministic tree reduction (4800 float4) --------
__global__ __launch_bounds__(256) void k_final(const float4* __restrict__ part,
                                               const float* __restrict__ att_loss,
                                               float* __restrict__ out) {
    __shared__ float4 red[256];
    int t = threadIdx.x;              // 256
    float4 s = make_float4(0.f, 0.f, 0.f, 0.f);
    for (int i = t; i < NELEM; i += 256) {
        float4 v = part[i];
        s.x += v.x; s.y += v.y; s.z += v.z; s.w += v.w;
    }
    red[t] = s;
    __syncthreads();
    for (int w = 128; w; w >>= 1) {
        if (t < w) {
            red[t].x += red[t + w].x; red[t].y += red[t + w].y;
            red[t].z += red[t + w].z; red[t].w += red[t + w].w;
        }
        __syncthreads();
    }
    if (t == 0) {
        out[0] = red[0].x / (float)NELEM + 0.1f * att_loss[0];
        out[1] = red[0].y / (float)NELEM;
        out[2] = red[0].z / (float)NELEM;
        out[3] = red[0].w / (float)NELEM;
    }
}

extern "C" void kernel_launch(void* const* d_in, const int* in_sizes, int n_in,
                              void* d_out, int out_size, void* d_ws, size_t ws_size,
                              hipStream_t stream) {
    const float* out_f        = (const float*)d_in[0];
    // d_in[1] = labels_support (unused by the reference's train path)
    const int*   labels_query = (const int*)d_in[2];
    const float* att_loss     = (const float*)d_in[3];
    float* out = (float*)d_out;

    // workspace layout
    float*  rowmean   = (float*)d_ws;                         // 51200 f
    float*  proto_all = rowmean + NROWS * NUM_SLOT;           // 320*8*640 f
    float*  pn2_all   = proto_all + NGROUP * NUM_SLOT * DD;   // 2560 f
    float4* part      = (float4*)(pn2_all + NGROUP * NUM_SLOT); // 4800 float4

    k_pass1<<<NGROUP + NELEM, 256, 0, stream>>>(out_f, rowmean, proto_all, pn2_all);
    k_elem<<<NELEM, 256, 0, stream>>>(out_f, rowmean, proto_all, pn2_all,
                                      labels_query, part);
    k_final<<<1, 256, 0, stream>>>(part, att_loss, out);
}

// Round 7
// 45.465 us; speedup vs baseline: 1.1617x; 1.1617x over previous
//
#include <hip/hip_runtime.h>

// Problem constants (match reference)
#define BB 64
#define N_WAY 5
#define N_SHOT 5
#define QUERY 15
#define NUM_SLOT 8
#define DD 640
#define IMGS (N_WAY * QUERY)      // 75
#define NS (BB * N_WAY * N_SHOT)  // 1600 support rows
#define NROWS 6400                // total rows
#define ROWSZ (NUM_SLOT * DD)     // 5120 floats per row
#define F4_PER_SLOT 160           // 640/4
#define NELEM (BB * IMGS)         // 4800 loss elements
#define NGROUP (BB * N_WAY)       // 320 support groups
#define NTASK 150                 // score tasks per batch (75 path1 + 75 path2)
#define TPB 8                     // tasks per k_score block (4 waves x 2 rounds)
#define SBLK 19                   // ceil(150/8) score blocks per batch
#define LBLK 19                   // ceil(4800/256) loss blocks

// ---------------- K1: single streaming pass over out_f ----------------
// rowmean[6400][8] (per-row slot means), proto_all[320][8][640] (shot-means,
// all slots), pn2_all[320][8] (||proto||^2, all slots).
__global__ __launch_bounds__(256) void k_pass1(const float* __restrict__ out_f,
                                               float* __restrict__ rowmean,
                                               float* __restrict__ proto_all,
                                               float* __restrict__ pn2_all) {
    int b = blockIdx.x;
    int t = threadIdx.x;
    int slot = t >> 5;            // 0..7
    int l = t & 31;
    if (b < NGROUP) {
        const int g = b;          // support group j*5+c
        float4 acc[5];
        #pragma unroll
        for (int k = 0; k < 5; ++k) acc[k] = make_float4(0.f, 0.f, 0.f, 0.f);
        #pragma unroll
        for (int sh = 0; sh < N_SHOT; ++sh) {
            const float4* p = (const float4*)(out_f +
                ((size_t)((g * N_SHOT + sh) * NUM_SLOT + slot)) * DD);
            float s = 0.f;
            #pragma unroll
            for (int k = 0; k < 5; ++k) {
                float4 v = p[l + k * 32];
                acc[k].x += v.x; acc[k].y += v.y; acc[k].z += v.z; acc[k].w += v.w;
                s += (v.x + v.y) + (v.z + v.w);
            }
            #pragma unroll
            for (int off = 16; off; off >>= 1) s += __shfl_down(s, off, 32);
            if (l == 0) rowmean[(g * N_SHOT + sh) * NUM_SLOT + slot] = s * (1.f / DD);
        }
        float4* pp = (float4*)(proto_all + ((size_t)(g * NUM_SLOT + slot)) * DD);
        float ssq = 0.f;
        #pragma unroll
        for (int k = 0; k < 5; ++k) {
            acc[k].x *= 0.2f; acc[k].y *= 0.2f; acc[k].z *= 0.2f; acc[k].w *= 0.2f;
            pp[l + k * 32] = acc[k];
            ssq += acc[k].x * acc[k].x + acc[k].y * acc[k].y
                 + acc[k].z * acc[k].z + acc[k].w * acc[k].w;
        }
        #pragma unroll
        for (int off = 16; off; off >>= 1) ssq += __shfl_down(ssq, off, 32);
        if (l == 0) pn2_all[g * NUM_SLOT + slot] = ssq;
    } else {
        int r = NS + (b - NGROUP);   // query row
        const float4* p = (const float4*)(out_f + (size_t)r * ROWSZ) + slot * F4_PER_SLOT;
        float s = 0.f;
        #pragma unroll
        for (int k = 0; k < 5; ++k) {
            float4 v = p[l + k * 32];
            s += (v.x + v.y) + (v.z + v.w);
        }
        #pragma unroll
        for (int off = 16; off; off >>= 1) s += __shfl_down(s, off, 32);
        if (l == 0) rowmean[r * NUM_SLOT + slot] = s * (1.f / DD);
    }
}

// ---------------- K2: cover-select + wave-parallel prefix argmax ----------------
// One block (one wave) per batch. Writes max_s, k_idx, p2c (selected ||p||^2).
__global__ __launch_bounds__(64) void k_select(const float* __restrict__ rowmean,
                                               const float* __restrict__ pn2_all,
                                               int* __restrict__ max_s,
                                               int* __restrict__ k_idx,
                                               float* __restrict__ p2c) {
    int j = blockIdx.x;           // 0..63
    int t = threadIdx.x;          // 0..63
    __shared__ float supm[N_WAY * NUM_SLOT];
    __shared__ int msS[N_WAY];
    __shared__ float qb[IMGS * NUM_SLOT];     // 600

    const float* qbase = rowmean + (size_t)(NS + j * IMGS) * NUM_SLOT;
    for (int i = t; i < IMGS * NUM_SLOT; i += 64) qb[i] = qbase[i];
    if (t < N_WAY * NUM_SLOT) {
        int c = t >> 3, s = t & 7;
        const float* sb = rowmean + (size_t)j * (N_WAY * N_SHOT * NUM_SLOT)
                          + c * (N_SHOT * NUM_SLOT) + s;
        float a = sb[0] + sb[8] + sb[16] + sb[24] + sb[32];
        supm[t] = a * 0.2f;
    }
    __syncthreads();

    // greedy cover select (serial, tiny; first-occurrence among untaken)
    if (t == 0) {
        unsigned taken = 0u;
        #pragma unroll
        for (int c = 0; c < N_WAY; ++c) {
            float best = -3.0e38f; int bi = 0;
            #pragma unroll
            for (int s = 0; s < NUM_SLOT; ++s) {
                float v = supm[c * NUM_SLOT + s];
                if (!((taken >> s) & 1u) && v > best) { best = v; bi = s; }
            }
            taken |= (1u << bi);
            msS[c] = bi;
            max_s[j * N_WAY + c] = bi;
        }
    }
    __syncthreads();
    int ms0 = msS[0], ms1 = msS[1], ms2 = msS[2], ms3 = msS[3], ms4 = msS[4];

    if (t < N_WAY) p2c[j * N_WAY + t] = pn2_all[(j * N_WAY + t) * NUM_SLOT + msS[t]];

    // per-step local argmax for step s = t (flat index s*5+c, first occurrence)
    float bv; int bi;
    {
        const float* q = &qb[t * NUM_SLOT];
        bv = q[ms0]; bi = t * N_WAY;
        float v;
        v = q[ms1]; if (v > bv) { bv = v; bi = t * N_WAY + 1; }
        v = q[ms2]; if (v > bv) { bv = v; bi = t * N_WAY + 2; }
        v = q[ms3]; if (v > bv) { bv = v; bi = t * N_WAY + 3; }
        v = q[ms4]; if (v > bv) { bv = v; bi = t * N_WAY + 4; }
    }
    // inclusive prefix scan; take later only if strictly greater
    #pragma unroll
    for (int off = 1; off < 64; off <<= 1) {
        float ov = __shfl_up(bv, off, 64);
        int   oi = __shfl_up(bi, off, 64);
        if (t >= off && !(bv > ov)) { bv = ov; bi = oi; }
    }
    k_idx[j * IMGS + t] = bi;
    float tv = __shfl(bv, 63, 64);
    int   ti = __shfl(bi, 63, 64);
    float bv2 = -3.0e38f; int bi2 = 0;
    if (t < IMGS - 64) {
        int s = 64 + t;
        const float* q = &qb[s * NUM_SLOT];
        bv2 = q[ms0]; bi2 = s * N_WAY;
        float v;
        v = q[ms1]; if (v > bv2) { bv2 = v; bi2 = s * N_WAY + 1; }
        v = q[ms2]; if (v > bv2) { bv2 = v; bi2 = s * N_WAY + 2; }
        v = q[ms3]; if (v > bv2) { bv2 = v; bi2 = s * N_WAY + 3; }
        v = q[ms4]; if (v > bv2) { bv2 = v; bi2 = s * N_WAY + 4; }
    }
    #pragma unroll
    for (int off = 1; off < 16; off <<= 1) {
        float ov = __shfl_up(bv2, off, 64);
        int   oi = __shfl_up(bi2, off, 64);
        if (t >= off && t < IMGS - 64 && !(bv2 > ov)) { bv2 = ov; bi2 = oi; }
    }
    if (t < IMGS - 64) {
        if (!(bv2 > tv)) { bv2 = tv; bi2 = ti; }
        k_idx[j * IMGS + 64 + t] = bi2;
    }
}

// ---------------- K3: dense score tensor, one wave per (batch, task) ----------
// task < 75:  score[j][task][n]    = dot(q(task, ms[task/15]), proto_n)
// task >= 75: m = task-75, (s2,c2) = k_idx[j*75+m]:
//             score[j][task][n]    = dot(q(s2, ms[c2]), proto_n)
// Protos (selected slots) staged in LDS once per block.
__global__ __launch_bounds__(256) void k_score(const float* __restrict__ out_f,
                                               const float* __restrict__ proto_all,
                                               const int* __restrict__ max_s,
                                               const int* __restrict__ k_idx,
                                               float* __restrict__ score) {
    int blk = blockIdx.x;          // j*SBLK + bt
    int j = blk / SBLK, bt = blk - j * SBLK;
    int t = threadIdx.x;           // 256
    int wave = t >> 6, lane = t & 63;

    __shared__ __align__(16) float protoS[N_WAY * DD];   // 12.8 KB
    __shared__ int msS[N_WAY];

    if (t < N_WAY) msS[t] = max_s[j * N_WAY + t];
    __syncthreads();
    // stage 5 selected protos
    for (int i = t; i < N_WAY * F4_PER_SLOT; i += 256) {
        int c = i / F4_PER_SLOT, r = i - c * F4_PER_SLOT;
        ((float4*)protoS)[i] = ((const float4*)(proto_all +
            ((size_t)((j * N_WAY + c) * NUM_SLOT + msS[c])) * DD))[r];
    }
    __syncthreads();

    #pragma unroll
    for (int rnd = 0; rnd < 2; ++rnd) {
        int task = bt * TPB + rnd * 4 + wave;
        if (task >= NTASK) continue;
        int row, sl;
        if (task < IMGS) {
            row = task;
            sl = msS[task / QUERY];
        } else {
            int m = task - IMGS;
            int kk = k_idx[j * IMGS + m];
            int s2 = kk / N_WAY, c2 = kk - s2 * N_WAY;
            row = s2;
            sl = msS[c2];
        }
        // lane owns floats [lane*10, lane*10+10) of the 640-dim vectors
        const float2* q = (const float2*)(out_f +
            (size_t)(NS + j * IMGS + row) * ROWSZ + sl * DD) + lane * 5;
        float2 qv[5];
        #pragma unroll
        for (int k = 0; k < 5; ++k) qv[k] = q[k];
        float acc[N_WAY] = {0, 0, 0, 0, 0};
        #pragma unroll
        for (int n = 0; n < N_WAY; ++n) {
            const float2* pp = (const float2*)(protoS + n * DD) + lane * 5;
            #pragma unroll
            for (int k = 0; k < 5; ++k) {
                float2 pv = pp[k];
                acc[n] += qv[k].x * pv.x + qv[k].y * pv.y;
            }
        }
        #pragma unroll
        for (int n = 0; n < N_WAY; ++n) {
            #pragma unroll
            for (int off = 32; off; off >>= 1)
                acc[n] += __shfl_down(acc[n], off, 64);
        }
        if (lane == 0) {
            float* dst = score + ((size_t)j * NTASK + task) * N_WAY;
            #pragma unroll
            for (int n = 0; n < N_WAY; ++n) dst[n] = acc[n];
        }
    }
}

// ---------------- K4: per-element softmax loss/acc (one thread per element) ----
__global__ __launch_bounds__(256) void k_loss2(const float* __restrict__ score,
                                               const float* __restrict__ p2c,
                                               const int* __restrict__ labels_query,
                                               float4* __restrict__ part) {
    int t = threadIdx.x;
    int e = blockIdx.x * 256 + t;      // element j*75+m
    float nll1 = 0.f, nll2 = 0.f, acc1 = 0.f, acc2 = 0.f;
    if (e < NELEM) {
        int j = e / IMGS, m = e - j * IMGS;
        int label = labels_query[e];
        const float* p2 = p2c + j * N_WAY;
        const float* sc1 = score + ((size_t)j * NTASK + m) * N_WAY;
        const float* sc2 = score + ((size_t)j * NTASK + IMGS + m) * N_WAY;
        // path 1: li_n = 2 q.p_n - ||p_n||^2 (||q||^2 cancels)
        {
            float li[N_WAY]; float mx = -3.0e38f;
            #pragma unroll
            for (int n = 0; n < N_WAY; ++n) { li[n] = 2.f * sc1[n] - p2[n]; mx = fmaxf(mx, li[n]); }
            float se = 0.f;
            #pragma unroll
            for (int n = 0; n < N_WAY; ++n) se += expf(li[n] - mx);
            float lse = mx + logf(se);
            int bi = 0; float bv = li[0];
            #pragma unroll
            for (int n = 1; n < N_WAY; ++n) if (li[n] > bv) { bv = li[n]; bi = n; }
            nll1 = -(li[label] - lse);
            acc1 = (bi == label) ? 1.f : 0.f;
        }
        // path 2
        {
            float li[N_WAY]; float mx = -3.0e38f;
            #pragma unroll
            for (int n = 0; n < N_WAY; ++n) { li[n] = 2.f * sc2[n] - p2[n]; mx = fmaxf(mx, li[n]); }
            float se = 0.f;
            #pragma unroll
            for (int n = 0; n < N_WAY; ++n) se += expf(li[n] - mx);
            float lse = mx + logf(se);
            int bi = 0; float bv = li[0];
            #pragma unroll
            for (int n = 1; n < N_WAY; ++n) if (li[n] > bv) { bv = li[n]; bi = n; }
            nll2 = -(li[label] - lse);
            acc2 = (bi == label) ? 1.f : 0.f;
        }
    }
    __shared__ float4 red[256];
    red[t] = make_float4(nll1, nll2, acc1, acc2);
    __syncthreads();
    for (int w = 128; w; w >>= 1) {
        if (t < w) {
            red[t].x += red[t + w].x; red[t].y += red[t + w].y;
            red[t].z += red[t + w].z; red[t].w += red[t + w].w;
        }
        __syncthreads();
    }
    if (t == 0) part[blockIdx.x] = red[0];
}

// ---------------- K5: final deterministic reduction (LBLK float4) --------------
__global__ __launch_bounds__(64) void k_final(const float4* __restrict__ part,
                                              const float* __restrict__ att_loss,
                                              float* __restrict__ out) {
    int t = threadIdx.x;              // 64
    float4 v = (t < LBLK) ? part[t] : make_float4(0.f, 0.f, 0.f, 0.f);
    #pragma unroll
    for (int off = 32; off; off >>= 1) {
        v.x += __shfl_down(v.x, off, 64);
        v.y += __shfl_down(v.y, off, 64);
        v.z += __shfl_down(v.z, off, 64);
        v.w += __shfl_down(v.w, off, 64);
    }
    if (t == 0) {
        out[0] = v.x / (float)NELEM + 0.1f * att_loss[0];
        out[1] = v.y / (float)NELEM;
        out[2] = v.z / (float)NELEM;
        out[3] = v.w / (float)NELEM;
    }
}

extern "C" void kernel_launch(void* const* d_in, const int* in_sizes, int n_in,
                              void* d_out, int out_size, void* d_ws, size_t ws_size,
                              hipStream_t stream) {
    const float* out_f        = (const float*)d_in[0];
    // d_in[1] = labels_support (unused by the reference's train path)
    const int*   labels_query = (const int*)d_in[2];
    const float* att_loss     = (const float*)d_in[3];
    float* out = (float*)d_out;

    // workspace layout
    float*  rowmean   = (float*)d_ws;                           // 51200 f
    float*  proto_all = rowmean + NROWS * NUM_SLOT;             // 320*8*640 f
    float*  pn2_all   = proto_all + NGROUP * NUM_SLOT * DD;     // 2560 f
    float*  score     = pn2_all + NGROUP * NUM_SLOT;            // 64*150*5 = 48000 f
    float*  p2c       = score + (size_t)BB * NTASK * N_WAY;     // 320 f
    float4* part      = (float4*)(p2c + NGROUP);                // LBLK float4
    int*    max_s     = (int*)(part + LBLK);                    // 320 i
    int*    k_idx     = max_s + NGROUP;                         // 4800 i

    k_pass1<<<NGROUP + NELEM, 256, 0, stream>>>(out_f, rowmean, proto_all, pn2_all);
    k_select<<<BB, 64, 0, stream>>>(rowmean, pn2_all, max_s, k_idx, p2c);
    k_score<<<BB * SBLK, 256, 0, stream>>>(out_f, proto_all, max_s, k_idx, score);
    k_loss2<<<LBLK, 256, 0, stream>>>(score, p2c, labels_query, part);
    k_final<<<1, 64, 0, stream>>>(part, att_loss, out);
}